// Round 2
// baseline (178.193 us; speedup 1.0000x reference)
//
#include <hip/hip_runtime.h>

// LRN: out[c] = x[c] / sqrt( sum_{i=max(0,c-128)}^{min(255,c+127)} x[i]^2 )
// (ALPHA/N = 1.0, K = 0, BETA = 0.5, ch = N = 256, half_n = 128)
//
// One wave (64 lanes) per pixel. Lane l owns channels 4l..4l+3 (float4).
// Wave inclusive scan of per-lane square-sums -> incl[] distributed across
// lanes. Window sums via 4 cross-lane shuffles:
//   c <= 128 : ws = incl[c+127]
//   c >= 129 : ws = total - incl[c-129]
// Index algebra (verified at c=0,125..130,255):
//   j=0: src lane (l+31)&63, elem 3 (both branches)
//   j=1..3: src lane l^32, elem j-1 (both branches)

__global__ __launch_bounds__(256) void lrn_kernel(const float* __restrict__ x,
                                                  float* __restrict__ out,
                                                  int npix) {
    const int lane = threadIdx.x & 63;
    const int waveInBlock = threadIdx.x >> 6;
    const int wavesPerGrid = gridDim.x * 4;

    for (int p = blockIdx.x * 4 + waveInBlock; p < npix; p += wavesPerGrid) {
        const float4* __restrict__ xv =
            reinterpret_cast<const float4*>(x) + (size_t)p * 64;
        float4 v = xv[lane];

        float sx = v.x * v.x;
        float sy = v.y * v.y;
        float sz = v.z * v.z;
        float sw = v.w * v.w;
        float s4 = sx + sy + sz + sw;

        // Inclusive wave scan over the 64 per-lane sums.
        float s = s4;
#pragma unroll
        for (int off = 1; off < 64; off <<= 1) {
            float t = __shfl_up(s, off, 64);
            if (lane >= off) s += t;
        }
        float total = __shfl(s, 63, 64);

        // In-lane inclusive prefix: incl[4l+j]
        float pre = s - s4;
        float i0 = pre + sx;
        float i1 = i0 + sy;
        float i2 = i1 + sz;
        float i3 = i2 + sw;

        // Window-boundary gathers.
        float a3 = __shfl(i3, (lane + 31) & 63, 64);
        int src = lane ^ 32;
        float b0 = __shfl(i0, src, 64);
        float b1 = __shfl(i1, src, 64);
        float b2 = __shfl(i2, src, 64);

        bool lo0 = (lane <= 32);  // c=4l   <= 128
        bool lo  = (lane <= 31);  // c=4l+j <= 128 for j>=1
        float ws0 = lo0 ? a3 : (total - a3);
        float ws1 = lo  ? b0 : (total - b0);
        float ws2 = lo  ? b1 : (total - b1);
        float ws3 = lo  ? b2 : (total - b2);

        // Match reference: scale = win**0.5, out = x / scale.
        // IEEE sqrt + IEEE div (NOT rsqrtf -> approx v_rsq_f32).
        float4 o;
        o.x = v.x / sqrtf(ws0);
        o.y = v.y / sqrtf(ws1);
        o.z = v.z / sqrtf(ws2);
        o.w = v.w / sqrtf(ws3);

        float4* __restrict__ ov =
            reinterpret_cast<float4*>(out) + (size_t)p * 64;
        ov[lane] = o;
    }
}

extern "C" void kernel_launch(void* const* d_in, const int* in_sizes, int n_in,
                              void* d_out, int out_size, void* d_ws, size_t ws_size,
                              hipStream_t stream) {
    const float* x = (const float*)d_in[0];
    float* out = (float*)d_out;
    int total = in_sizes[0];           // 32*56*56*256 = 25,690,112
    int npix = total / 256;            // 100,352 pixels

    // 2048 blocks x 4 waves/block, grid-stride over pixels:
    // 8 blocks/CU on 256 CUs -> plenty of TLP for a memory-bound kernel.
    int blocks = 2048;
    lrn_kernel<<<blocks, 256, 0, stream>>>(x, out, npix);
}

// Round 6
// 171.238 us; speedup vs baseline: 1.0406x; 1.0406x over previous
//
#include <hip/hip_runtime.h>

// LRN: out[c] = x[c] / sqrt( sum_{i=max(0,c-128)}^{min(255,c+127)} x[i]^2 )
// (ALPHA/N = 1.0, K = 0, BETA = 0.5, ch = N = 256, half_n = 128)
//
// One wave per PIXEL GROUP of 4: lane l owns channels 4l..4l+3 of each of 4
// consecutive pixels (16B vector loads). The 4 wave-scans are interleaved
// stage-by-stage so the serial ds_bpermute latency of one pixel's scan hides
// under the other three (round-2 evidence: 2.5 TB/s, VALUBusy 38% ->
// latency-bound on the single shfl chain, not BW-bound).
//
// Window lookups (verified at c=0,125..130,255):
//   c <= 128 : ws = incl[c+127]    c >= 129 : ws = total - incl[c-129]
//   j=0: src lane (l+31)&63, elem 3 (both branches)
//   j=1..3: src lane l^32, elem j-1 (both branches)

#define PIX 4

// Native clang vector: __builtin_nontemporal_* requires this, not
// HIP_vector_type<float,4>.
typedef float f32x4 __attribute__((ext_vector_type(4)));

__global__ __launch_bounds__(256) void lrn_kernel(const float* __restrict__ x,
                                                  float* __restrict__ out,
                                                  int npix) {
    const int lane = threadIdx.x & 63;
    const int wave = threadIdx.x >> 6;
    const int pbase = (blockIdx.x * 4 + wave) * PIX;
    if (pbase + PIX > npix) return;  // grid sized exactly; guard is free

    const f32x4* __restrict__ xv = reinterpret_cast<const f32x4*>(x);

    // 4 loads issued back-to-back: 4 KB of HBM in flight per wave.
    f32x4 v[PIX];
#pragma unroll
    for (int p = 0; p < PIX; ++p) {
        const f32x4* src = xv + (size_t)(pbase + p) * 64 + lane;
        v[p] = __builtin_nontemporal_load(src);
    }

    float sx[PIX], sy[PIX], sz[PIX], sw[PIX], s4[PIX], s[PIX];
#pragma unroll
    for (int p = 0; p < PIX; ++p) {
        sx[p] = v[p].x * v[p].x;
        sy[p] = v[p].y * v[p].y;
        sz[p] = v[p].z * v[p].z;
        sw[p] = v[p].w * v[p].w;
        s4[p] = sx[p] + sy[p] + sz[p] + sw[p];
        s[p]  = s4[p];
    }

    // Inclusive wave scan, 4 independent chains interleaved per stage.
#pragma unroll
    for (int off = 1; off < 64; off <<= 1) {
        float t[PIX];
#pragma unroll
        for (int p = 0; p < PIX; ++p) t[p] = __shfl_up(s[p], off, 64);
#pragma unroll
        for (int p = 0; p < PIX; ++p)
            if (lane >= off) s[p] += t[p];
    }

    // total via readlane (SALU broadcast, off the LDS pipe).
    float total[PIX];
#pragma unroll
    for (int p = 0; p < PIX; ++p)
        total[p] = __uint_as_float(
            __builtin_amdgcn_readlane(__float_as_uint(s[p]), 63));

    // In-lane inclusive prefixes incl[4l+j].
    float i0[PIX], i1[PIX], i2[PIX], i3[PIX];
#pragma unroll
    for (int p = 0; p < PIX; ++p) {
        float pre = s[p] - s4[p];
        i0[p] = pre + sx[p];
        i1[p] = i0[p] + sy[p];
        i2[p] = i1[p] + sz[p];
        i3[p] = i2[p] + sw[p];
    }

    // Window-boundary gathers, interleaved across pixels.
    const int srcA = (lane + 31) & 63;
    const int srcB = lane ^ 32;
    float a3[PIX], b0[PIX], b1[PIX], b2[PIX];
#pragma unroll
    for (int p = 0; p < PIX; ++p) a3[p] = __shfl(i3[p], srcA, 64);
#pragma unroll
    for (int p = 0; p < PIX; ++p) b0[p] = __shfl(i0[p], srcB, 64);
#pragma unroll
    for (int p = 0; p < PIX; ++p) b1[p] = __shfl(i1[p], srcB, 64);
#pragma unroll
    for (int p = 0; p < PIX; ++p) b2[p] = __shfl(i2[p], srcB, 64);

    const bool lo0 = (lane <= 32);  // c=4l   <= 128
    const bool lo  = (lane <= 31);  // c=4l+j <= 128 for j>=1

    f32x4* __restrict__ ov = reinterpret_cast<f32x4*>(out);
#pragma unroll
    for (int p = 0; p < PIX; ++p) {
        float ws0 = lo0 ? a3[p] : (total[p] - a3[p]);
        float ws1 = lo  ? b0[p] : (total[p] - b0[p]);
        float ws2 = lo  ? b1[p] : (total[p] - b1[p]);
        float ws3 = lo  ? b2[p] : (total[p] - b2[p]);

        // Bit-identical math to the round-2 passing kernel: IEEE sqrt + div.
        f32x4 o;
        o.x = v[p].x / sqrtf(ws0);
        o.y = v[p].y / sqrtf(ws1);
        o.z = v[p].z / sqrtf(ws2);
        o.w = v[p].w / sqrtf(ws3);

        // Output is never re-read: nt store keeps the L3 input-resident.
        f32x4* dst = ov + (size_t)(pbase + p) * 64 + lane;
        __builtin_nontemporal_store(o, dst);
    }
}

extern "C" void kernel_launch(void* const* d_in, const int* in_sizes, int n_in,
                              void* d_out, int out_size, void* d_ws, size_t ws_size,
                              hipStream_t stream) {
    const float* x = (const float*)d_in[0];
    float* out = (float*)d_out;
    int total = in_sizes[0];           // 32*56*56*256 = 25,690,112
    int npix = total / 256;            // 100,352 pixels

    // 16 pixels per block (4 waves x 4 pixels) -> 6272 blocks exactly.
    int blocks = (npix + 4 * PIX - 1) / (4 * PIX);
    lrn_kernel<<<blocks, 256, 0, stream>>>(x, out, npix);
}